// Round 1
// baseline (1760.813 us; speedup 1.0000x reference)
//
#include <hip/hip_runtime.h>
#include <math.h>

#define NN 50000
#define RR 8
#define EE 800000
#define RN 400000            // RR * NN
#define DIN 128
#define K1 1024              // RR * DIN
#define KTOT 1152            // K1 + DIN
#define NBLK 391             // ceil(RN / 1024)

// ---------------- workspace layout (bytes) ----------------
#define OFF_U    0UL                    // u: [NN][RR*128] f32 = 204,800,000
#define OFF_H0   204800000UL            // h0: [NN][128] f32 = 25,600,000
#define OFF_H1   230400000UL            // h1: [NN][128] f32 = 25,600,000
#define OFF_OFFS 256000000UL            // offsets: (RN+1) ints -> 1,600,128 padded
#define OFF_CUR  257600128UL            // cursor/hist: RN ints = 1,600,000
#define OFF_SRT  259200128UL            // sorted_src: EE ints = 3,200,000
#define OFF_BS   262400128UL            // block sums: 1024 ints
#define WS_NEED  262404224UL

// ---------------- edge preprocessing ----------------
__global__ void k_hist(const int* __restrict__ ei, const int* __restrict__ et,
                       int* __restrict__ hist) {
    int e = blockIdx.x * blockDim.x + threadIdx.x;
    if (e >= EE) return;
    int dst = ei[EE + e];
    int r = et[e];
    atomicAdd(&hist[dst * RR + r], 1);
}

__global__ void k_scan1(const int* __restrict__ hist, int* __restrict__ offs,
                        int* __restrict__ bsums) {
    __shared__ int tmp[1024];
    int tid = threadIdx.x;
    int g = blockIdx.x * 1024 + tid;
    int v = (g < RN) ? hist[g] : 0;
    tmp[tid] = v;
    __syncthreads();
    for (int off = 1; off < 1024; off <<= 1) {
        int t = tmp[tid];
        if (tid >= off) t += tmp[tid - off];
        __syncthreads();
        tmp[tid] = t;
        __syncthreads();
    }
    if (g < RN) offs[g] = tmp[tid] - v;          // exclusive within block
    if (tid == 1023) bsums[blockIdx.x] = tmp[1023];
}

__global__ void k_scan2(int* __restrict__ bsums) {
    __shared__ int tmp[1024];
    int tid = threadIdx.x;
    int v = (tid < NBLK) ? bsums[tid] : 0;
    tmp[tid] = v;
    __syncthreads();
    for (int off = 1; off < 1024; off <<= 1) {
        int t = tmp[tid];
        if (tid >= off) t += tmp[tid - off];
        __syncthreads();
        tmp[tid] = t;
        __syncthreads();
    }
    if (tid < NBLK) bsums[tid] = tmp[tid] - v;   // exclusive
}

__global__ void k_scan3(int* __restrict__ offs, const int* __restrict__ bsums) {
    int g = blockIdx.x * 1024 + threadIdx.x;
    if (g < RN) offs[g] += bsums[blockIdx.x];
    else if (g == RN) offs[RN] = EE;
}

__global__ void k_scatter(const int* __restrict__ ei, const int* __restrict__ et,
                          const int* __restrict__ offs, int* __restrict__ cur,
                          int* __restrict__ ssrc) {
    int e = blockIdx.x * blockDim.x + threadIdx.x;
    if (e >= EE) return;
    int src = ei[e];
    int dst = ei[EE + e];
    int r = et[e];
    int s = dst * RR + r;
    int pos = offs[s] + atomicAdd(&cur[s], 1);
    ssrc[pos] = src;
}

// ---------------- per-layer: segment mean aggregation ----------------
// one block (128 threads) per segment s = dst*8 + r; u[s*128 + i] = mean
__global__ void k_agg(const float* __restrict__ h, const int* __restrict__ offs,
                      const int* __restrict__ ssrc, float* __restrict__ u) {
    int s = blockIdx.x;
    int i = threadIdx.x;
    int beg = offs[s], end = offs[s + 1];
    float acc = 0.f;
    for (int e = beg; e < end; ++e) {
        int src = ssrc[e];                       // uniform across block
        acc += h[(size_t)src * DIN + i];
    }
    int cnt = end - beg;
    float inv = 1.0f / (float)max(cnt, 1);
    u[(size_t)s * DIN + i] = acc * inv;
}

// ---------------- per-layer GEMM: out = [u|h] @ [W;root] + bias ----------------
// A(n,k) = k<1024 ? u[n*1024+k] : h[n*128+k-1024]   (M=NN, K=1152)
// B(k,o) = k<1024 ? W[k*O+o]    : root[(k-1024)*O+o]
template<bool RELU>
__global__ __launch_bounds__(256) void k_gemm(
        const float* __restrict__ u, const float* __restrict__ h,
        const float* __restrict__ W, const float* __restrict__ root,
        const float* __restrict__ bias, float* __restrict__ out, int O) {
    __shared__ alignas(16) float As[16][68];
    __shared__ alignas(16) float Bs[16][68];
    int m0 = blockIdx.x * 64;
    int o0 = blockIdx.y * 64;
    int tid = threadIdx.x;
    int trow = (tid >> 4) * 4;
    int tcol = (tid & 15) * 4;
    int la_m = tid >> 4;      // 0..15
    int la_k = tid & 15;      // 0..15
    int lb_k = tid >> 6;      // 0..3
    int lb_o = tid & 63;      // 0..63
    float c[4][4] = {};

    for (int kt = 0; kt < KTOT; kt += 16) {
        bool useU = (kt < K1);
#pragma unroll
        for (int j = 0; j < 4; ++j) {
            int n = m0 + la_m + j * 16;
            float v = 0.f;
            if (n < NN) {
                int k = kt + la_k;
                v = useU ? u[(size_t)n * K1 + k]
                         : h[(size_t)n * DIN + (k - K1)];
            }
            As[la_k][la_m + j * 16] = v;
        }
#pragma unroll
        for (int j = 0; j < 4; ++j) {
            int k = kt + lb_k + j * 4;
            int o = o0 + lb_o;
            float v = useU ? W[(size_t)k * O + o]
                           : root[(size_t)(k - K1) * O + o];
            Bs[lb_k + j * 4][lb_o] = v;
        }
        __syncthreads();
#pragma unroll
        for (int kk = 0; kk < 16; ++kk) {
            float4 a = *reinterpret_cast<const float4*>(&As[kk][trow]);
            float4 b = *reinterpret_cast<const float4*>(&Bs[kk][tcol]);
            float av[4] = {a.x, a.y, a.z, a.w};
            float bv[4] = {b.x, b.y, b.z, b.w};
#pragma unroll
            for (int x = 0; x < 4; ++x)
#pragma unroll
                for (int y = 0; y < 4; ++y)
                    c[x][y] += av[x] * bv[y];
        }
        __syncthreads();
    }
#pragma unroll
    for (int x = 0; x < 4; ++x) {
        int n = m0 + trow + x;
        if (n >= NN) continue;
#pragma unroll
        for (int y = 0; y < 4; ++y) {
            int o = o0 + tcol + y;
            float v = c[x][y] + bias[o];
            if (RELU) v = fmaxf(v, 0.f);
            out[(size_t)n * O + o] = v;
        }
    }
}

// ---------------- final log_softmax over 64 cols ----------------
__global__ void k_logsoftmax(const float* __restrict__ in, float* __restrict__ out) {
    int row = blockIdx.x * 4 + (threadIdx.x >> 6);
    int lane = threadIdx.x & 63;
    if (row >= NN) return;
    float v = in[(size_t)row * 64 + lane];
    float m = v;
#pragma unroll
    for (int off = 32; off; off >>= 1) m = fmaxf(m, __shfl_xor(m, off, 64));
    float e = expf(v - m);
    float s = e;
#pragma unroll
    for (int off = 32; off; off >>= 1) s += __shfl_xor(s, off, 64);
    out[(size_t)row * 64 + lane] = v - m - logf(s);
}

extern "C" void kernel_launch(void* const* d_in, const int* in_sizes, int n_in,
                              void* d_out, int out_size, void* d_ws, size_t ws_size,
                              hipStream_t stream) {
    const float* x  = (const float*)d_in[0];
    const int*   ei = (const int*)d_in[1];
    const int*   et = (const int*)d_in[2];
    const float* W[4]    = {(const float*)d_in[3], (const float*)d_in[6],
                            (const float*)d_in[9], (const float*)d_in[12]};
    const float* root[4] = {(const float*)d_in[4], (const float*)d_in[7],
                            (const float*)d_in[10], (const float*)d_in[13]};
    const float* bias[4] = {(const float*)d_in[5], (const float*)d_in[8],
                            (const float*)d_in[11], (const float*)d_in[14]};

    if (ws_size < WS_NEED) return;  // workspace too small -> will fail visibly

    char* ws = (char*)d_ws;
    float* u    = (float*)(ws + OFF_U);
    float* h0   = (float*)(ws + OFF_H0);
    float* h1   = (float*)(ws + OFF_H1);
    int*   offs = (int*)(ws + OFF_OFFS);
    int*   cur  = (int*)(ws + OFF_CUR);
    int*   ssrc = (int*)(ws + OFF_SRT);
    int*   bsums= (int*)(ws + OFF_BS);

    // ---- one-time edge sort by segment key s = dst*8 + etype ----
    hipMemsetAsync(cur, 0, RN * sizeof(int), stream);
    k_hist<<<(EE + 255) / 256, 256, 0, stream>>>(ei, et, cur);
    k_scan1<<<NBLK, 1024, 0, stream>>>(cur, offs, bsums);
    k_scan2<<<1, 1024, 0, stream>>>(bsums);
    k_scan3<<<NBLK, 1024, 0, stream>>>(offs, bsums);
    hipMemsetAsync(cur, 0, RN * sizeof(int), stream);
    k_scatter<<<(EE + 255) / 256, 256, 0, stream>>>(ei, et, offs, cur, ssrc);

    dim3 g2(782, 2), g1(782, 1);
    // layer 1: x -> h0
    k_agg<<<RN, 128, 0, stream>>>(x, offs, ssrc, u);
    k_gemm<true><<<g2, 256, 0, stream>>>(u, x, W[0], root[0], bias[0], h0, 128);
    // layer 2: h0 -> h1
    k_agg<<<RN, 128, 0, stream>>>(h0, offs, ssrc, u);
    k_gemm<true><<<g2, 256, 0, stream>>>(u, h0, W[1], root[1], bias[1], h1, 128);
    // layer 3: h1 -> h0
    k_agg<<<RN, 128, 0, stream>>>(h1, offs, ssrc, u);
    k_gemm<true><<<g2, 256, 0, stream>>>(u, h1, W[2], root[2], bias[2], h0, 128);
    // layer 4: h0 -> h1 (O=64, no relu)
    k_agg<<<RN, 128, 0, stream>>>(h0, offs, ssrc, u);
    k_gemm<false><<<g1, 256, 0, stream>>>(u, h0, W[3], root[3], bias[3], h1, 64);
    // log_softmax -> d_out
    k_logsoftmax<<<(NN + 3) / 4, 256, 0, stream>>>(h1, (float*)d_out);
}

// Round 2
// 601.926 us; speedup vs baseline: 2.9253x; 2.9253x over previous
//
#include <hip/hip_runtime.h>
#include <math.h>

#define NN 50000
#define RR 8
#define EE 800000
#define RN 400000            // RR * NN
#define DIN 128
#define K1 1024              // RR * DIN
#define KTOT 1152            // K1 + DIN
#define NBLK 391             // ceil(RN / 1024)

// ---------------- workspace layout (bytes) ----------------
#define OFF_U    0UL           // u bf16: [RN][128]            = 102,400,000
#define OFF_HB0  102400000UL   // h bf16: [NN][128]            =  12,800,000
#define OFF_HB1  115200000UL   // h bf16: [NN][128]            =  12,800,000
#define OFF_XB   128000000UL   // x bf16: [NN][128]            =  12,800,000
#define OFF_LG   140800000UL   // logits f32: [NN][64]         =  12,800,000
#define OFF_WT   153600000UL   // W^T bf16: 4 x 147456 elems   =   1,179,648
#define OFF_OFFS 154780160UL   // offsets: (RN+1) ints         =   1,600,128
#define OFF_CUR  156380288UL   // cursor/hist: RN ints         =   1,600,000
#define OFF_SRT  157980288UL   // sorted_src: EE ints          =   3,200,000
#define OFF_BS   161180288UL   // block sums                   =       4,096
#define WS_NEED  161184384UL

typedef short bf16x8 __attribute__((ext_vector_type(8)));
typedef float f32x4 __attribute__((ext_vector_type(4)));

__device__ __forceinline__ unsigned f2bf(float f) {       // RNE f32 -> bf16 bits
    unsigned x = __float_as_uint(f);
    return (x + 0x7fffu + ((x >> 16) & 1u)) >> 16;
}
__device__ __forceinline__ float bflo(unsigned p) { return __uint_as_float(p << 16); }
__device__ __forceinline__ float bfhi(unsigned p) { return __uint_as_float(p & 0xffff0000u); }

// ---------------- one-time converts ----------------
__global__ void k_cvt(const float* __restrict__ x, ushort* __restrict__ xb) {
    int i = blockIdx.x * 256 + threadIdx.x;
    if (i >= NN * 32) return;                 // float4 granules
    float4 v = ((const float4*)x)[i];
    ushort4 o;
    o.x = (ushort)f2bf(v.x); o.y = (ushort)f2bf(v.y);
    o.z = (ushort)f2bf(v.z); o.w = (ushort)f2bf(v.w);
    ((ushort4*)xb)[i] = o;
}

// build W^T[o][k] bf16, k in [0,1152): k<1024 -> W[k>>7][k&127][o], else root[k-1024][o]
__global__ void k_wt(const float* __restrict__ W, const float* __restrict__ Rt,
                     ushort* __restrict__ WT, int O) {
    int o = blockIdx.x;
    for (int k = threadIdx.x; k < KTOT; k += 256) {
        float v = (k < K1)
            ? W[(size_t)(k >> 7) * 128 * O + (size_t)(k & 127) * O + o]
            : Rt[(size_t)(k - K1) * O + o];
        WT[(size_t)o * KTOT + k] = (ushort)f2bf(v);
    }
}

// ---------------- edge preprocessing (counting sort by s = dst*8 + r) ----------------
__global__ void k_hist(const int* __restrict__ ei, const int* __restrict__ et,
                       int* __restrict__ hist) {
    int e = blockIdx.x * blockDim.x + threadIdx.x;
    if (e >= EE) return;
    atomicAdd(&hist[ei[EE + e] * RR + et[e]], 1);
}

__global__ void k_scan1(const int* __restrict__ hist, int* __restrict__ offs,
                        int* __restrict__ bsums) {
    __shared__ int tmp[1024];
    int tid = threadIdx.x;
    int g = blockIdx.x * 1024 + tid;
    int v = (g < RN) ? hist[g] : 0;
    tmp[tid] = v;
    __syncthreads();
    for (int off = 1; off < 1024; off <<= 1) {
        int t = tmp[tid];
        if (tid >= off) t += tmp[tid - off];
        __syncthreads();
        tmp[tid] = t;
        __syncthreads();
    }
    if (g < RN) offs[g] = tmp[tid] - v;
    if (tid == 1023) bsums[blockIdx.x] = tmp[1023];
}

__global__ void k_scan2(int* __restrict__ bsums) {
    __shared__ int tmp[1024];
    int tid = threadIdx.x;
    int v = (tid < NBLK) ? bsums[tid] : 0;
    tmp[tid] = v;
    __syncthreads();
    for (int off = 1; off < 1024; off <<= 1) {
        int t = tmp[tid];
        if (tid >= off) t += tmp[tid - off];
        __syncthreads();
        tmp[tid] = t;
        __syncthreads();
    }
    if (tid < NBLK) bsums[tid] = tmp[tid] - v;
}

__global__ void k_scan3(int* __restrict__ offs, const int* __restrict__ bsums) {
    int g = blockIdx.x * 1024 + threadIdx.x;
    if (g < RN) offs[g] += bsums[blockIdx.x];
    else if (g == RN) offs[RN] = EE;
}

__global__ void k_scatter(const int* __restrict__ ei, const int* __restrict__ et,
                          const int* __restrict__ offs, int* __restrict__ cur,
                          int* __restrict__ ssrc) {
    int e = blockIdx.x * blockDim.x + threadIdx.x;
    if (e >= EE) return;
    int s = ei[EE + e] * RR + et[e];
    ssrc[offs[s] + atomicAdd(&cur[s], 1)] = ei[e];
}

// ---------------- per-layer: segment mean aggregation (bf16 in/out, f32 acc) ----------------
// one wave per segment, grid-stride; lane handles 2 cols via bf16x2 words
__global__ __launch_bounds__(256) void k_agg(const ushort* __restrict__ hb,
        const int* __restrict__ offs, const int* __restrict__ ssrc,
        ushort* __restrict__ u) {
    int gt = blockIdx.x * 256 + threadIdx.x;
    int wid = gt >> 6, lane = gt & 63;
    int nw = (gridDim.x * 256) >> 6;
    const unsigned* h2 = (const unsigned*)hb;
    unsigned* u2 = (unsigned*)u;
    for (int s = wid; s < RN; s += nw) {
        int beg = offs[s], end = offs[s + 1];
        float a0 = 0.f, a1 = 0.f;
        int e = beg;
        for (; e + 1 < end; e += 2) {          // 2-deep to break load chain
            int s0 = ssrc[e], s1 = ssrc[e + 1];
            unsigned p0 = h2[s0 * 64 + lane];
            unsigned p1 = h2[s1 * 64 + lane];
            a0 += bflo(p0) + bflo(p1);
            a1 += bfhi(p0) + bfhi(p1);
        }
        if (e < end) {
            unsigned p = h2[ssrc[e] * 64 + lane];
            a0 += bflo(p); a1 += bfhi(p);
        }
        float inv = 1.0f / (float)max(end - beg, 1);
        a0 *= inv; a1 *= inv;
        u2[s * 64 + lane] = f2bf(a0) | (f2bf(a1) << 16);
    }
}

// ---------------- MFMA GEMM: out[n][o] = [u|h](n,:) @ WT(o,:)^T + bias ----------------
// BM=64 rows/block; BK=64; A staged in LDS (XOR-swizzled, rule #21 both-sides);
// B fragments read straight from bf16 W^T (K-contiguous, L2-resident).
template<int WAVES_M, int WAVES_N, int MT, bool RELU, bool OUTF32>
__global__ __launch_bounds__(256) void k_gemm(
        const ushort* __restrict__ u, const ushort* __restrict__ hb,
        const ushort* __restrict__ WT, const float* __restrict__ bias,
        void* __restrict__ outv) {
    constexpr int BN = WAVES_N * 32;
    __shared__ ushort As[64 * 64];
    const int tid = threadIdx.x;
    const int lane = tid & 63;
    const int w = tid >> 6;
    const int wr = w / WAVES_N;
    const int wc = w % WAVES_N;
    const int m0 = blockIdx.x * 64;
    f32x4 acc[MT][2] = {};

    for (int kt = 0; kt < KTOT; kt += 64) {
        const ushort* base; int rstride, kc;
        if (kt < K1) { base = u;  rstride = 1024; kc = kt; }
        else         { base = hb; rstride = 128;  kc = kt - K1; }
#pragma unroll
        for (int i = 0; i < 2; ++i) {
            int slot = i * 256 + tid;          // 0..511 -> (row, col16)
            int r = slot >> 3, c16 = slot & 7;
            int n = min(m0 + r, NN - 1);       // clamp tail (masked at epilogue)
            uint4 v = *(const uint4*)(base + (size_t)n * rstride + kc + c16 * 8);
            *(uint4*)(&As[r * 64 + ((c16 ^ (r & 7)) * 8)]) = v;
        }
        __syncthreads();
#pragma unroll
        for (int kk = 0; kk < 2; ++kk) {
            bf16x8 bfr[2];
#pragma unroll
            for (int nt = 0; nt < 2; ++nt) {
                int col = wc * 32 + nt * 16 + (lane & 15);
                int k = kt + kk * 32 + (lane >> 4) * 8;
                bfr[nt] = *(const bf16x8*)(WT + (size_t)col * KTOT + k);
            }
#pragma unroll
            for (int mt = 0; mt < MT; ++mt) {
                int row = wr * MT * 16 + mt * 16 + (lane & 15);
                int c16 = (kk * 4 + (lane >> 4)) ^ (row & 7);
                bf16x8 a = *(const bf16x8*)(&As[row * 64 + c16 * 8]);
#pragma unroll
                for (int nt = 0; nt < 2; ++nt)
                    acc[mt][nt] = __builtin_amdgcn_mfma_f32_16x16x32_bf16(
                        a, bfr[nt], acc[mt][nt], 0, 0, 0);
            }
        }
        __syncthreads();
    }
#pragma unroll
    for (int mt = 0; mt < MT; ++mt) {
#pragma unroll
        for (int nt = 0; nt < 2; ++nt) {
            int col = wc * 32 + nt * 16 + (lane & 15);
            float bs = bias[col];
#pragma unroll
            for (int j = 0; j < 4; ++j) {
                int row = m0 + wr * MT * 16 + mt * 16 + (lane >> 4) * 4 + j;
                if (row >= NN) continue;
                float v = acc[mt][nt][j] + bs;
                if (RELU) v = fmaxf(v, 0.f);
                if (OUTF32) ((float*)outv)[(size_t)row * BN + col] = v;
                else ((ushort*)outv)[(size_t)row * BN + col] = (ushort)f2bf(v);
            }
        }
    }
}

// ---------------- final log_softmax over 64 cols ----------------
__global__ void k_logsoftmax(const float* __restrict__ in, float* __restrict__ out) {
    int row = blockIdx.x * 4 + (threadIdx.x >> 6);
    int lane = threadIdx.x & 63;
    if (row >= NN) return;
    float v = in[(size_t)row * 64 + lane];
    float m = v;
#pragma unroll
    for (int off = 32; off; off >>= 1) m = fmaxf(m, __shfl_xor(m, off, 64));
    float e = expf(v - m);
    float s = e;
#pragma unroll
    for (int off = 32; off; off >>= 1) s += __shfl_xor(s, off, 64);
    out[(size_t)row * 64 + lane] = v - m - logf(s);
}

extern "C" void kernel_launch(void* const* d_in, const int* in_sizes, int n_in,
                              void* d_out, int out_size, void* d_ws, size_t ws_size,
                              hipStream_t stream) {
    const float* x  = (const float*)d_in[0];
    const int*   ei = (const int*)d_in[1];
    const int*   et = (const int*)d_in[2];
    const float* W[4]    = {(const float*)d_in[3], (const float*)d_in[6],
                            (const float*)d_in[9], (const float*)d_in[12]};
    const float* root[4] = {(const float*)d_in[4], (const float*)d_in[7],
                            (const float*)d_in[10], (const float*)d_in[13]};
    const float* bias[4] = {(const float*)d_in[5], (const float*)d_in[8],
                            (const float*)d_in[11], (const float*)d_in[14]};

    if (ws_size < WS_NEED) return;

    char* ws = (char*)d_ws;
    ushort* u    = (ushort*)(ws + OFF_U);
    ushort* hb0  = (ushort*)(ws + OFF_HB0);
    ushort* hb1  = (ushort*)(ws + OFF_HB1);
    ushort* xb   = (ushort*)(ws + OFF_XB);
    float*  lg   = (float*)(ws + OFF_LG);
    ushort* WT   = (ushort*)(ws + OFF_WT);
    int*   offs  = (int*)(ws + OFF_OFFS);
    int*   cur   = (int*)(ws + OFF_CUR);
    int*   ssrc  = (int*)(ws + OFF_SRT);
    int*   bsums = (int*)(ws + OFF_BS);
    ushort* WTl[4] = {WT, WT + 147456, WT + 2 * 147456, WT + 3 * 147456};

    // one-time converts
    k_cvt<<<(NN * 32 + 255) / 256, 256, 0, stream>>>(x, xb);
    k_wt<<<128, 256, 0, stream>>>(W[0], root[0], WTl[0], 128);
    k_wt<<<128, 256, 0, stream>>>(W[1], root[1], WTl[1], 128);
    k_wt<<<128, 256, 0, stream>>>(W[2], root[2], WTl[2], 128);
    k_wt<<<64,  256, 0, stream>>>(W[3], root[3], WTl[3], 64);

    // edge sort by segment key
    hipMemsetAsync(cur, 0, RN * sizeof(int), stream);
    k_hist<<<(EE + 255) / 256, 256, 0, stream>>>(ei, et, cur);
    k_scan1<<<NBLK, 1024, 0, stream>>>(cur, offs, bsums);
    k_scan2<<<1, 1024, 0, stream>>>(bsums);
    k_scan3<<<NBLK, 1024, 0, stream>>>(offs, bsums);
    hipMemsetAsync(cur, 0, RN * sizeof(int), stream);
    k_scatter<<<(EE + 255) / 256, 256, 0, stream>>>(ei, et, offs, cur, ssrc);

    const int GEMM_G = (NN + 63) / 64;   // 782
    // layer 1: xb -> hb0
    k_agg<<<2048, 256, 0, stream>>>(xb, offs, ssrc, u);
    k_gemm<1, 4, 4, true, false><<<GEMM_G, 256, 0, stream>>>(u, xb, WTl[0], bias[0], hb0);
    // layer 2: hb0 -> hb1
    k_agg<<<2048, 256, 0, stream>>>(hb0, offs, ssrc, u);
    k_gemm<1, 4, 4, true, false><<<GEMM_G, 256, 0, stream>>>(u, hb0, WTl[1], bias[1], hb1);
    // layer 3: hb1 -> hb0
    k_agg<<<2048, 256, 0, stream>>>(hb1, offs, ssrc, u);
    k_gemm<1, 4, 4, true, false><<<GEMM_G, 256, 0, stream>>>(u, hb1, WTl[2], bias[2], hb0);
    // layer 4: hb0 -> logits f32 (O=64, no relu)
    k_agg<<<2048, 256, 0, stream>>>(hb0, offs, ssrc, u);
    k_gemm<2, 2, 2, false, true><<<GEMM_G, 256, 0, stream>>>(u, hb0, WTl[3], bias[3], lg);
    // log_softmax -> d_out
    k_logsoftmax<<<(NN + 3) / 4, 256, 0, stream>>>(lg, (float*)d_out);
}